// Round 1
// baseline (1049.638 us; speedup 1.0000x reference)
//
#include <hip/hip_runtime.h>
#include <stdint.h>

typedef __attribute__((ext_vector_type(4))) float f32x4;
typedef __attribute__((ext_vector_type(8))) short bf16x8;
typedef __attribute__((ext_vector_type(4))) short bf16x4;

#define MFMA(a, b, c) __builtin_amdgcn_mfma_f32_16x16x32_bf16(a, b, c, 0, 0, 0)

__device__ __forceinline__ short f2bf(float f) {
    unsigned u = __builtin_bit_cast(unsigned, f);
    u = (u + 0x7fffu + ((u >> 16) & 1u)) >> 16;
    return (short)u;
}

__device__ __forceinline__ unsigned cvt_pk_bf16(float lo, float hi) {
    unsigned r;
    asm("v_cvt_pk_bf16_f32 %0, %1, %2" : "=v"(r) : "v"(lo), "v"(hi));
    return r;
}

__device__ __forceinline__ void g2l16(const void* g, void* l) {
    __builtin_amdgcn_global_load_lds(
        (const __attribute__((address_space(1))) unsigned*)g,
        (__attribute__((address_space(3))) unsigned*)l, 16, 0, 0);
}

union U8 { bf16x8 v; unsigned u[4]; };
union V8 { bf16x8 v; bf16x4 h[2]; };

// ---------------- fp32 -> bf16 convert (8 elems / thread) ----------------
__global__ void cvt_bf16_kernel(const float* __restrict__ src,
                                short* __restrict__ dst, int n8) {
    int i = blockIdx.x * blockDim.x + threadIdx.x;
    if (i >= n8) return;
    const f32x4* s = (const f32x4*)src;
    f32x4 a = s[2 * i], b = s[2 * i + 1];
    bf16x8 o;
    o[0] = f2bf(a[0]); o[1] = f2bf(a[1]); o[2] = f2bf(a[2]); o[3] = f2bf(a[3]);
    o[4] = f2bf(b[0]); o[5] = f2bf(b[1]); o[6] = f2bf(b[2]); o[7] = f2bf(b[3]);
    ((bf16x8*)dst)[i] = o;
}

// ---------------- GEMM1: qkv = X @ Wi^T + bi, scatter to q/k/vt ----------
__global__ __launch_bounds__(256, 2) void gemm_qkv_kernel(
    const short* __restrict__ A, const short* __restrict__ W,
    const float* __restrict__ bias,
    short* __restrict__ qb, short* __restrict__ kb, short* __restrict__ vtb) {
    __shared__ short As[128 * 32];
    __shared__ short Bs[128 * 32];
    __shared__ short scrS[4][16 * 24];  // per-wave epilogue repack, stride 24
    const int tid = threadIdx.x;
    const int wave = tid >> 6, lane = tid & 63;
    const int al = lane >> 4, ac = lane & 15;
    const int m0 = blockIdx.x * 128;
    const int n0 = blockIdx.y * 128;
    const int wm = wave & 1, wn = wave >> 1;

    const int crow = tid >> 2, ccol = (tid & 3) * 8;
    const short* Ag0 = A + (m0 + crow) * 1024 + ccol;
    const short* Ag1 = A + (m0 + crow + 64) * 1024 + ccol;
    const short* Wg0 = W + (n0 + crow) * 1024 + ccol;
    const short* Wg1 = W + (n0 + crow + 64) * 1024 + ccol;
    short* lA0 = &As[wave * 512];
    short* lA1 = &As[2048 + wave * 512];
    short* lB0 = &Bs[wave * 512];
    short* lB1 = &Bs[2048 + wave * 512];

    f32x4 acc[4][4];
#pragma unroll
    for (int mi = 0; mi < 4; mi++)
#pragma unroll
        for (int ni = 0; ni < 4; ni++) acc[mi][ni] = (f32x4){0.f, 0.f, 0.f, 0.f};

    for (int k0 = 0; k0 < 1024; k0 += 32) {
        __syncthreads();
        g2l16(Ag0 + k0, lA0);
        g2l16(Ag1 + k0, lA1);
        g2l16(Wg0 + k0, lB0);
        g2l16(Wg1 + k0, lB1);
        __syncthreads();
        bf16x8 af[4], bfr[4];
#pragma unroll
        for (int i = 0; i < 4; i++) {
            af[i] = *(const bf16x8*)&As[(wm * 64 + i * 16 + ac) * 32 + al * 8];
            bfr[i] = *(const bf16x8*)&Bs[(wn * 64 + i * 16 + ac) * 32 + al * 8];
        }
#pragma unroll
        for (int mi = 0; mi < 4; mi++)
#pragma unroll
            for (int ni = 0; ni < 4; ni++)
                acc[mi][ni] = MFMA(af[mi], bfr[ni], acc[mi][ni]);
    }

    // ---- epilogue: per-wave LDS repack -> 8B coalesced stores ----
    const int n0w = n0 + wn * 64;
    const int which = n0w >> 10;  // 0=q, 1=k, 2=v (wave-uniform)
    short* scr = scrS[wave];
    const int lr = lane >> 2;   // read-phase row 0..15
    const int lq = lane & 3;    // read-phase quad
    const int bglob = m0 >> 11; // batch (uniform per block)

#pragma unroll
    for (int mi = 0; mi < 4; mi++) {
#pragma unroll
        for (int ni = 0; ni < 4; ni++) {
            const int col0 = n0w + ni * 16;
            const float bvc = bias[col0 + ac];
            if (which == 2) {
                // transpose in LDS: scr[d=ac][l=al*4+r], packed b64 write
                bf16x4 pk;
#pragma unroll
                for (int r = 0; r < 4; r++) pk[r] = f2bf(acc[mi][ni][r] + bvc);
                *(bf16x4*)&scr[ac * 24 + al * 4] = pk;
                bf16x4 v4 = *(const bf16x4*)&scr[lr * 24 + lq * 4];
                const int colv = col0 + lr;
                const int e = colv & 1023;
                const int h = e >> 6, d = e & 63;
                const int row0 = m0 + wm * 64 + mi * 16 + lq * 4;
                const int l0 = row0 & 2047;
                *(bf16x4*)&vtb[(((bglob * 16 + h) * 64 + d) * 2048) + l0] = v4;
            } else {
                // q pre-scaled by 1/sqrt(D) * log2(e) so attn uses exp2 directly
                const float sc = (which == 0) ? 0.18033688f : 1.0f;
#pragma unroll
                for (int r = 0; r < 4; r++)
                    scr[(al * 4 + r) * 24 + ac] = f2bf((acc[mi][ni][r] + bvc) * sc);
                bf16x4 v4 = *(const bf16x4*)&scr[lr * 24 + lq * 4];
                const int col = col0 + lq * 4;
                const int e = col & 1023;
                const int h = e >> 6, d0 = e & 63;
                const int row = m0 + wm * 64 + mi * 16 + lr;
                const int l = row & 2047;
                short* dst = (which == 0) ? qb : kb;
                *(bf16x4*)&dst[(((bglob * 16 + h) * 2048 + l) * 64) + d0] = v4;
            }
        }
    }
}

// ---------------- Fused flash attention: register-only, swapped QK ------
// One wave per 16 q-rows of one (b,h). No LDS, no barriers.
// s^T = mfma(K, Q): lane (ac,al) holds q = ac, k = ni*16 + al*4 + r.
// Softmax is lane-local (+2 shfl_xor for cross-al); P packed via cvt_pk
// feeds PV mfma directly using a relabeled k-slot map (dot-product slot
// permutation invariance); V fragments read with the matching addressing.
#define ATTN_STEP(K0, BC, BN)                                                 \
  {                                                                           \
    const int kp_ = ((K0) + 64 < 2048) ? (K0) + 64 : 1984;                    \
    f32x4 s_[4];                                                              \
    __builtin_amdgcn_s_setprio(1);                                            \
    _Pragma("unroll") for (int ni = 0; ni < 4; ni++) {                        \
        s_[ni] = MFMA(kf[2 * ni], qf0, ((f32x4){0.f, 0.f, 0.f, 0.f}));        \
        s_[ni] = MFMA(kf[2 * ni + 1], qf1, s_[ni]);                           \
    }                                                                         \
    __builtin_amdgcn_s_setprio(0);                                            \
    /* K prefetch for next block (regs dead after the MFMAs above) */         \
    _Pragma("unroll") for (int ni = 0; ni < 4; ni++) {                        \
        kf[2 * ni] = *(const bf16x8*)&kpb[(kp_ + ni * 16) * 64];              \
        kf[2 * ni + 1] = *(const bf16x8*)&kpb[(kp_ + ni * 16) * 64 + 32];     \
    }                                                                         \
    /* V fragments for THIS block: slot j <-> k=32s+16(j>>2)+al*4+(j&3) */    \
    V8 vf_[4][2];                                                             \
    _Pragma("unroll") for (int nd = 0; nd < 4; nd++)                          \
        _Pragma("unroll") for (int ss = 0; ss < 2; ss++) {                    \
            const short* vp_ = vpb + nd * (16 * 2048) + (K0) + 32 * ss;       \
            vf_[nd][ss].h[0] = *(const bf16x4*)vp_;                           \
            vf_[nd][ss].h[1] = *(const bf16x4*)(vp_ + 16);                    \
        }                                                                     \
    /* bias prefetch for next block (HBM-cold stream, double-buffered) */     \
    _Pragma("unroll") for (int ni = 0; ni < 4; ni++)                          \
        BN[ni] = __builtin_nontemporal_load((const f32x4*)&bp[kp_ + ni * 16]);\
    float t_[16];                                                             \
    _Pragma("unroll") for (int ni = 0; ni < 4; ni++)                          \
        _Pragma("unroll") for (int r = 0; r < 4; r++)                         \
            t_[ni * 4 + r] = __builtin_fmaf(BC[ni][r], L2E, s_[ni][r]);       \
    float ma_[8];                                                             \
    _Pragma("unroll") for (int i = 0; i < 8; i++)                             \
        ma_[i] = fmaxf(t_[i], t_[8 + i]);                                     \
    float ml_ = fmaxf(fmaxf(fmaxf(ma_[0], ma_[1]), fmaxf(ma_[2], ma_[3])),    \
                      fmaxf(fmaxf(ma_[4], ma_[5]), fmaxf(ma_[6], ma_[7])));   \
    ml_ = fmaxf(ml_, __shfl_xor(ml_, 16));                                    \
    ml_ = fmaxf(ml_, __shfl_xor(ml_, 32));                                    \
    if (__any(ml_ > m_i + 8.f)) { /* defer-max: rare rescale */               \
        const float mn_ = fmaxf(m_i, ml_);                                    \
        const float a_ = __builtin_exp2f(m_i - mn_);                          \
        m_i = mn_;                                                            \
        l_i *= a_;                                                            \
        _Pragma("unroll") for (int r = 0; r < 4; r++) {                       \
            const float ar_ = __shfl(a_, al20 + r);                           \
            _Pragma("unroll") for (int nd = 0; nd < 4; nd++)                  \
                o[nd][r] *= ar_;                                              \
        }                                                                     \
    }                                                                         \
    float p_[16];                                                             \
    _Pragma("unroll") for (int i = 0; i < 16; i++)                            \
        p_[i] = __builtin_exp2f(t_[i] - m_i);                                 \
    float ps0_ = 0.f, ps1_ = 0.f, ps2_ = 0.f, ps3_ = 0.f;                     \
    _Pragma("unroll") for (int r = 0; r < 4; r++) {                           \
        ps0_ += p_[r]; ps1_ += p_[4 + r];                                     \
        ps2_ += p_[8 + r]; ps3_ += p_[12 + r];                                \
    }                                                                         \
    l_i += (ps0_ + ps1_) + (ps2_ + ps3_);                                     \
    U8 pf0_, pf1_;                                                            \
    _Pragma("unroll") for (int w = 0; w < 4; w++) {                           \
        pf0_.u[w] = cvt_pk_bf16(p_[2 * w], p_[2 * w + 1]);                    \
        pf1_.u[w] = cvt_pk_bf16(p_[8 + 2 * w], p_[8 + 2 * w + 1]);            \
    }                                                                         \
    __builtin_amdgcn_s_setprio(1);                                            \
    _Pragma("unroll") for (int nd = 0; nd < 4; nd++) {                        \
        o[nd] = MFMA(pf0_.v, vf_[nd][0].v, o[nd]);                            \
        o[nd] = MFMA(pf1_.v, vf_[nd][1].v, o[nd]);                            \
    }                                                                         \
    __builtin_amdgcn_s_setprio(0);                                            \
  }

__global__ __launch_bounds__(64, 3) void attn_kernel(
    const short* __restrict__ Qb, const short* __restrict__ Kb,
    const short* __restrict__ Vtb, const float* __restrict__ bias,
    short* __restrict__ Ctx) {
    const int lane = threadIdx.x & 63;
    const int ac = lane & 15, al = lane >> 4;
    const int al20 = al * 20;  // shfl src for q = al*4+r: lane al*16+al*4+r
    // XCD-aware swizzle: XCD x gets bh in {4x..4x+3} so K/V (2MB/quad)
    // stays resident in that XCD's L2.
    const int bid = blockIdx.x;
    const int bh = (bid & 7) * 4 + ((bid >> 3) >> 7);
    const int q0 = ((bid >> 3) & 127) * 16;
    const long long kvbase = (long long)bh * (2048 * 64);
    const float L2E = 1.44269504088896340736f;

    const short* qp = Qb + kvbase + (q0 + ac) * 64 + al * 8;
    const bf16x8 qf0 = *(const bf16x8*)qp;
    const bf16x8 qf1 = *(const bf16x8*)(qp + 32);
    const float* bp = bias + ((long long)bh * 2048 + q0 + ac) * 2048 + al * 4;
    const short* kpb = Kb + kvbase + ac * 64 + al * 8;
    const short* vpb = Vtb + kvbase + ac * 2048 + al * 4;

    float m_i = -1e30f, l_i = 0.f;
    f32x4 o[4];
#pragma unroll
    for (int i = 0; i < 4; i++) o[i] = (f32x4){0.f, 0.f, 0.f, 0.f};

    bf16x8 kf[8];
#pragma unroll
    for (int ni = 0; ni < 4; ni++) {
        kf[2 * ni] = *(const bf16x8*)&kpb[(ni * 16) * 64];
        kf[2 * ni + 1] = *(const bf16x8*)&kpb[(ni * 16) * 64 + 32];
    }
    f32x4 bcA[4], bcB[4];
#pragma unroll
    for (int ni = 0; ni < 4; ni++)
        bcA[ni] = __builtin_nontemporal_load((const f32x4*)&bp[ni * 16]);

    for (int k0 = 0; k0 < 2048; k0 += 128) {
        ATTN_STEP(k0, bcA, bcB);
        ATTN_STEP(k0 + 64, bcB, bcA);
    }

    float lt = l_i + __shfl_xor(l_i, 16);
    lt += __shfl_xor(lt, 32);
    const float inv = 1.f / lt;
    const int b_ = bh >> 4, h_ = bh & 15;
    short* cp = Ctx + (long long)(b_ * 2048 + q0) * 1024 + h_ * 64 + ac;
#pragma unroll
    for (int r = 0; r < 4; r++) {
        const float ir_ = __shfl(inv, al20 + r);
        const int row = al * 4 + r;
#pragma unroll
        for (int nd = 0; nd < 4; nd++)
            cp[(long long)row * 1024 + nd * 16] = f2bf(o[nd][r] * ir_);
    }
}

// ---------------- GEMM2: out = Ctx @ Wo^T + bo (fp32 out) ----------------
__global__ __launch_bounds__(256, 2) void gemm_out_kernel(
    const short* __restrict__ A, const short* __restrict__ W,
    const float* __restrict__ bias, float* __restrict__ out) {
    __shared__ short As[128 * 32];
    __shared__ short Bs[128 * 32];
    __shared__ float scrF[4][16 * 28];  // per-wave fp32 repack, stride 28
    const int tid = threadIdx.x;
    const int wave = tid >> 6, lane = tid & 63;
    const int al = lane >> 4, ac = lane & 15;
    const int m0 = blockIdx.x * 128;
    const int n0 = blockIdx.y * 128;
    const int wm = wave & 1, wn = wave >> 1;

    const int crow = tid >> 2, ccol = (tid & 3) * 8;
    const short* Ag0 = A + (m0 + crow) * 1024 + ccol;
    const short* Ag1 = A + (m0 + crow + 64) * 1024 + ccol;
    const short* Wg0 = W + (n0 + crow) * 1024 + ccol;
    const short* Wg1 = W + (n0 + crow + 64) * 1024 + ccol;
    short* lA0 = &As[wave * 512];
    short* lA1 = &As[2048 + wave * 512];
    short* lB0 = &Bs[wave * 512];
    short* lB1 = &Bs[2048 + wave * 512];

    f32x4 acc[4][4];
#pragma unroll
    for (int mi = 0; mi < 4; mi++)
#pragma unroll
        for (int ni = 0; ni < 4; ni++) acc[mi][ni] = (f32x4){0.f, 0.f, 0.f, 0.f};

    for (int k0 = 0; k0 < 1024; k0 += 32) {
        __syncthreads();
        g2l16(Ag0 + k0, lA0);
        g2l16(Ag1 + k0, lA1);
        g2l16(Wg0 + k0, lB0);
        g2l16(Wg1 + k0, lB1);
        __syncthreads();
        bf16x8 af[4], bfr[4];
#pragma unroll
        for (int i = 0; i < 4; i++) {
            af[i] = *(const bf16x8*)&As[(wm * 64 + i * 16 + ac) * 32 + al * 8];
            bfr[i] = *(const bf16x8*)&Bs[(wn * 64 + i * 16 + ac) * 32 + al * 8];
        }
#pragma unroll
        for (int mi = 0; mi < 4; mi++)
#pragma unroll
            for (int ni = 0; ni < 4; ni++)
                acc[mi][ni] = MFMA(af[mi], bfr[ni], acc[mi][ni]);
    }

    float* scr = scrF[wave];
    const int lr = lane >> 2, lq = lane & 3;
#pragma unroll
    for (int mi = 0; mi < 4; mi++) {
#pragma unroll
        for (int ni = 0; ni < 4; ni++) {
            const int col0 = n0 + wn * 64 + ni * 16;
            const float bvc = bias[col0 + ac];
#pragma unroll
            for (int r = 0; r < 4; r++)
                scr[(al * 4 + r) * 28 + ac] = acc[mi][ni][r] + bvc;
            f32x4 v4 = *(const f32x4*)&scr[lr * 28 + lq * 4];
            const int row = m0 + wm * 64 + mi * 16 + lr;
            *(f32x4*)&out[row * 1024 + col0 + lq * 4] = v4;
        }
    }
}

extern "C" void kernel_launch(void* const* d_in, const int* in_sizes, int n_in,
                              void* d_out, int out_size, void* d_ws,
                              size_t ws_size, hipStream_t stream) {
    const float* X = (const float*)d_in[0];
    const float* keb = (const float*)d_in[1];
    const float* Wi = (const float*)d_in[2];
    const float* bi = (const float*)d_in[3];
    const float* Wo = (const float*)d_in[4];
    const float* bo = (const float*)d_in[5];
    float* out = (float*)d_out;

    char* ws = (char*)d_ws;
    short* Xb  = (short*)(ws);              //  8 MB  [4096,1024]
    short* Wib = (short*)(ws + 8388608);    //  6 MB  [3072,1024]
    short* Wob = (short*)(ws + 14680064);   //  2 MB  [1024,1024]
    short* Qb  = (short*)(ws + 16777216);   //  8 MB  [bh][l][d] (pre-scaled by 0.125*log2e)
    short* Kb  = (short*)(ws + 25165824);   //  8 MB  [bh][l][d]
    short* Vtb = (short*)(ws + 33554432);   //  8 MB  [bh][d][l]
    short* Ctx = (short*)(ws + 41943040);   //  8 MB  [4096,1024]

    cvt_bf16_kernel<<<dim3(524288 / 256), 256, 0, stream>>>(X, Xb, 524288);
    cvt_bf16_kernel<<<dim3(393216 / 256), 256, 0, stream>>>(Wi, Wib, 393216);
    cvt_bf16_kernel<<<dim3(131072 / 256), 256, 0, stream>>>(Wo, Wob, 131072);
    gemm_qkv_kernel<<<dim3(32, 24), 256, 0, stream>>>(Xb, Wib, bi, Qb, Kb, Vtb);
    attn_kernel<<<dim3(4096), 64, 0, stream>>>(Qb, Kb, Vtb, keb, Ctx);
    gemm_out_kernel<<<dim3(32, 8), 256, 0, stream>>>(Ctx, Wob, bo, out);
}

// Round 2
// 806.095 us; speedup vs baseline: 1.3021x; 1.3021x over previous
//
#include <hip/hip_runtime.h>
#include <stdint.h>

typedef __attribute__((ext_vector_type(4))) float f32x4;
typedef __attribute__((ext_vector_type(8))) short bf16x8;
typedef __attribute__((ext_vector_type(4))) short bf16x4;

#define MFMA(a, b, c) __builtin_amdgcn_mfma_f32_16x16x32_bf16(a, b, c, 0, 0, 0)

__device__ __forceinline__ short f2bf(float f) {
    unsigned u = __builtin_bit_cast(unsigned, f);
    u = (u + 0x7fffu + ((u >> 16) & 1u)) >> 16;
    return (short)u;
}

__device__ __forceinline__ unsigned cvt_pk_bf16(float lo, float hi) {
    unsigned r;
    asm("v_cvt_pk_bf16_f32 %0, %1, %2" : "=v"(r) : "v"(lo), "v"(hi));
    return r;
}

__device__ __forceinline__ void g2l16(const void* g, void* l) {
    __builtin_amdgcn_global_load_lds(
        (const __attribute__((address_space(1))) unsigned*)g,
        (__attribute__((address_space(3))) unsigned*)l, 16, 0, 0);
}

union U8 { bf16x8 v; unsigned u[4]; };
union V8 { bf16x8 v; bf16x4 h[2]; };

// ---------------- fp32 -> bf16 convert (8 elems / thread) ----------------
__global__ void cvt_bf16_kernel(const float* __restrict__ src,
                                short* __restrict__ dst, int n8) {
    int i = blockIdx.x * blockDim.x + threadIdx.x;
    if (i >= n8) return;
    const f32x4* s = (const f32x4*)src;
    f32x4 a = s[2 * i], b = s[2 * i + 1];
    bf16x8 o;
    o[0] = f2bf(a[0]); o[1] = f2bf(a[1]); o[2] = f2bf(a[2]); o[3] = f2bf(a[3]);
    o[4] = f2bf(b[0]); o[5] = f2bf(b[1]); o[6] = f2bf(b[2]); o[7] = f2bf(b[3]);
    ((bf16x8*)dst)[i] = o;
}

// ---------------- GEMM1: qkv = X @ Wi^T + bi, scatter to q/k/vt ----------
__global__ __launch_bounds__(256, 2) void gemm_qkv_kernel(
    const short* __restrict__ A, const short* __restrict__ W,
    const float* __restrict__ bias,
    short* __restrict__ qb, short* __restrict__ kb, short* __restrict__ vtb) {
    __shared__ short As[128 * 32];
    __shared__ short Bs[128 * 32];
    __shared__ short scrS[4][16 * 24];  // per-wave epilogue repack, stride 24
    const int tid = threadIdx.x;
    const int wave = tid >> 6, lane = tid & 63;
    const int al = lane >> 4, ac = lane & 15;
    const int m0 = blockIdx.x * 128;
    const int n0 = blockIdx.y * 128;
    const int wm = wave & 1, wn = wave >> 1;

    const int crow = tid >> 2, ccol = (tid & 3) * 8;
    const short* Ag0 = A + (m0 + crow) * 1024 + ccol;
    const short* Ag1 = A + (m0 + crow + 64) * 1024 + ccol;
    const short* Wg0 = W + (n0 + crow) * 1024 + ccol;
    const short* Wg1 = W + (n0 + crow + 64) * 1024 + ccol;
    short* lA0 = &As[wave * 512];
    short* lA1 = &As[2048 + wave * 512];
    short* lB0 = &Bs[wave * 512];
    short* lB1 = &Bs[2048 + wave * 512];

    f32x4 acc[4][4];
#pragma unroll
    for (int mi = 0; mi < 4; mi++)
#pragma unroll
        for (int ni = 0; ni < 4; ni++) acc[mi][ni] = (f32x4){0.f, 0.f, 0.f, 0.f};

    for (int k0 = 0; k0 < 1024; k0 += 32) {
        __syncthreads();
        g2l16(Ag0 + k0, lA0);
        g2l16(Ag1 + k0, lA1);
        g2l16(Wg0 + k0, lB0);
        g2l16(Wg1 + k0, lB1);
        __syncthreads();
        bf16x8 af[4], bfr[4];
#pragma unroll
        for (int i = 0; i < 4; i++) {
            af[i] = *(const bf16x8*)&As[(wm * 64 + i * 16 + ac) * 32 + al * 8];
            bfr[i] = *(const bf16x8*)&Bs[(wn * 64 + i * 16 + ac) * 32 + al * 8];
        }
#pragma unroll
        for (int mi = 0; mi < 4; mi++)
#pragma unroll
            for (int ni = 0; ni < 4; ni++)
                acc[mi][ni] = MFMA(af[mi], bfr[ni], acc[mi][ni]);
    }

    // ---- epilogue: per-wave LDS repack -> 8B coalesced stores ----
    const int n0w = n0 + wn * 64;
    const int which = n0w >> 10;  // 0=q, 1=k, 2=v (wave-uniform)
    short* scr = scrS[wave];
    const int lr = lane >> 2;   // read-phase row 0..15
    const int lq = lane & 3;    // read-phase quad
    const int bglob = m0 >> 11; // batch (uniform per block)

#pragma unroll
    for (int mi = 0; mi < 4; mi++) {
#pragma unroll
        for (int ni = 0; ni < 4; ni++) {
            const int col0 = n0w + ni * 16;
            const float bvc = bias[col0 + ac];
            if (which == 2) {
                // transpose in LDS: scr[d=ac][l=al*4+r], packed b64 write
                bf16x4 pk;
#pragma unroll
                for (int r = 0; r < 4; r++) pk[r] = f2bf(acc[mi][ni][r] + bvc);
                *(bf16x4*)&scr[ac * 24 + al * 4] = pk;
                bf16x4 v4 = *(const bf16x4*)&scr[lr * 24 + lq * 4];
                const int colv = col0 + lr;
                const int e = colv & 1023;
                const int h = e >> 6, d = e & 63;
                const int row0 = m0 + wm * 64 + mi * 16 + lq * 4;
                const int l0 = row0 & 2047;
                *(bf16x4*)&vtb[(((bglob * 16 + h) * 64 + d) * 2048) + l0] = v4;
            } else {
                // q pre-scaled by 1/sqrt(D) * log2(e) so attn uses exp2 directly
                const float sc = (which == 0) ? 0.18033688f : 1.0f;
#pragma unroll
                for (int r = 0; r < 4; r++)
                    scr[(al * 4 + r) * 24 + ac] = f2bf((acc[mi][ni][r] + bvc) * sc);
                bf16x4 v4 = *(const bf16x4*)&scr[lr * 24 + lq * 4];
                const int col = col0 + lq * 4;
                const int e = col & 1023;
                const int h = e >> 6, d0 = e & 63;
                const int row = m0 + wm * 64 + mi * 16 + lr;
                const int l = row & 2047;
                short* dst = (which == 0) ? qb : kb;
                *(bf16x4*)&dst[(((bglob * 16 + h) * 2048 + l) * 64) + d0] = v4;
            }
        }
    }
}

// ---------------- Fused flash attention ----------------------------------
// Block = 256 thr (4 waves) = 64 q-rows of one (b,h); waves share K/V tiles
// staged in LDS (double-buffered, XOR-swizzled storage via pre-swizzled
// global source; rule #21). Swapped-QK register softmax retained.
// Per step: STAGE(next) [pinned] -> K frags/QK -> V frags -> softmax ->
// bias prefetch(next, NT, reg dbuf) -> PV -> vmcnt(4)+barrier (bias stays
// in flight across the barrier; stage drained).
#define STAGE(B_, KB_)                                                        \
  {                                                                           \
    g2l16(Kg + ((KB_) + sr0) * 64 + scs0, &Ks[B_][sw * 512]);                 \
    g2l16(Kg + ((KB_) + sr1) * 64 + scs1, &Ks[B_][2048 + sw * 512]);          \
    g2l16(Vg + sr0 * 2048 + (KB_) + scs0, &Vs[B_][sw * 512]);                 \
    g2l16(Vg + sr1 * 2048 + (KB_) + scs1, &Vs[B_][2048 + sw * 512]);          \
  }

#define ATTN_STEP(T, CURB, BC, BN)                                            \
  {                                                                           \
    const int tn_ = ((T) + 1 < 32) ? (T) + 1 : 31;                            \
    const int kn_ = tn_ * 64;                                                 \
    STAGE((CURB) ^ 1, kn_);                                                   \
    __builtin_amdgcn_sched_barrier(0);                                        \
    f32x4 s_[4];                                                              \
    __builtin_amdgcn_s_setprio(1);                                            \
    _Pragma("unroll") for (int ni = 0; ni < 4; ni++) {                        \
        const int ko_ = (ni * 16 + ac) * 64;                                  \
        const bf16x8 kf0_ = *(const bf16x8*)&Ks[CURB][ko_ + (ca_ << 3)];      \
        const bf16x8 kf1_ = *(const bf16x8*)&Ks[CURB][ko_ + ((ca_ ^ 4) << 3)];\
        s_[ni] = MFMA(kf0_, qf0, ((f32x4){0.f, 0.f, 0.f, 0.f}));              \
        s_[ni] = MFMA(kf1_, qf1, s_[ni]);                                     \
    }                                                                         \
    __builtin_amdgcn_s_setprio(0);                                            \
    V8 vf_[4][2];                                                             \
    _Pragma("unroll") for (int nd = 0; nd < 4; nd++) {                        \
        const int vo_ = (nd * 16 + ac) * 64 + inner_;                         \
        _Pragma("unroll") for (int ss = 0; ss < 2; ss++) {                    \
            vf_[nd][ss].h[0] =                                                \
                *(const bf16x4*)&Vs[CURB][vo_ + (((4 * ss + ch_) ^ rs_) << 3)]; \
            vf_[nd][ss].h[1] =                                                \
                *(const bf16x4*)&Vs[CURB][vo_ + (((4 * ss + 2 + ch_) ^ rs_) << 3)]; \
        }                                                                     \
    }                                                                         \
    float t_[16];                                                             \
    _Pragma("unroll") for (int ni = 0; ni < 4; ni++)                          \
        _Pragma("unroll") for (int r = 0; r < 4; r++)                         \
            t_[ni * 4 + r] = __builtin_fmaf(BC[ni][r], L2E, s_[ni][r]);       \
    float ma_[8];                                                             \
    _Pragma("unroll") for (int i = 0; i < 8; i++)                             \
        ma_[i] = fmaxf(t_[i], t_[8 + i]);                                     \
    float ml_ = fmaxf(fmaxf(fmaxf(ma_[0], ma_[1]), fmaxf(ma_[2], ma_[3])),    \
                      fmaxf(fmaxf(ma_[4], ma_[5]), fmaxf(ma_[6], ma_[7])));   \
    ml_ = fmaxf(ml_, __shfl_xor(ml_, 16));                                    \
    ml_ = fmaxf(ml_, __shfl_xor(ml_, 32));                                    \
    if (__any(ml_ > m_i + 8.f)) { /* defer-max: rare rescale */               \
        const float mn_ = fmaxf(m_i, ml_);                                    \
        const float a_ = __builtin_exp2f(m_i - mn_);                          \
        m_i = mn_;                                                            \
        l_i *= a_;                                                            \
        _Pragma("unroll") for (int r = 0; r < 4; r++) {                       \
            const float ar_ = __shfl(a_, al20 + r);                           \
            _Pragma("unroll") for (int nd = 0; nd < 4; nd++)                  \
                o[nd][r] *= ar_;                                              \
        }                                                                     \
    }                                                                         \
    float p_[16];                                                             \
    _Pragma("unroll") for (int i = 0; i < 16; i++)                            \
        p_[i] = __builtin_exp2f(t_[i] - m_i);                                 \
    float ps0_ = 0.f, ps1_ = 0.f, ps2_ = 0.f, ps3_ = 0.f;                     \
    _Pragma("unroll") for (int r = 0; r < 4; r++) {                           \
        ps0_ += p_[r]; ps1_ += p_[4 + r];                                     \
        ps2_ += p_[8 + r]; ps3_ += p_[12 + r];                                \
    }                                                                         \
    l_i += (ps0_ + ps1_) + (ps2_ + ps3_);                                     \
    _Pragma("unroll") for (int ni = 0; ni < 4; ni++)                          \
        BN[ni] = __builtin_nontemporal_load((const f32x4*)&bp[kn_ + ni * 16]);\
    U8 pf0_, pf1_;                                                            \
    _Pragma("unroll") for (int w = 0; w < 4; w++) {                           \
        pf0_.u[w] = cvt_pk_bf16(p_[2 * w], p_[2 * w + 1]);                    \
        pf1_.u[w] = cvt_pk_bf16(p_[8 + 2 * w], p_[8 + 2 * w + 1]);            \
    }                                                                         \
    __builtin_amdgcn_s_setprio(1);                                            \
    _Pragma("unroll") for (int nd = 0; nd < 4; nd++) {                        \
        o[nd] = MFMA(pf0_.v, vf_[nd][0].v, o[nd]);                            \
        o[nd] = MFMA(pf1_.v, vf_[nd][1].v, o[nd]);                            \
    }                                                                         \
    __builtin_amdgcn_s_setprio(0);                                            \
    asm volatile("s_waitcnt vmcnt(4) lgkmcnt(0)" ::: "memory");               \
    __builtin_amdgcn_s_barrier();                                             \
    __builtin_amdgcn_sched_barrier(0);                                        \
  }

__global__ __launch_bounds__(256, 3) void attn_kernel(
    const short* __restrict__ Qb, const short* __restrict__ Kb,
    const short* __restrict__ Vtb, const float* __restrict__ bias,
    short* __restrict__ Ctx) {
    __shared__ short Ks[2][64 * 64];
    __shared__ short Vs[2][64 * 64];
    const int tid = threadIdx.x;
    const int wave = tid >> 6, lane = tid & 63;
    const int ac = lane & 15, al = lane >> 4;
    const int al20 = al * 20;  // shfl src for q=al*4+r: lane al*16+al*4+r
    const int bid = blockIdx.x;
    // XCD swizzle: XCD x hosts bh in {4x..4x+3} (K/V quad = 2MB -> L2-resident)
    const int bh = (bid & 7) * 4 + ((bid >> 3) >> 5);
    const int q0 = ((bid >> 3) & 31) * 64 + wave * 16;
    const long long kvbase = (long long)bh * (2048 * 64);
    const float L2E = 1.44269504088896340736f;

    // stage-side indices (per-lane source swizzle; LDS dest is linear)
    const int sw = wave;
    const int sr0 = sw * 8 + (lane >> 3);        // instr0 rows 0..31
    const int sr1 = 32 + sw * 8 + (lane >> 3);   // instr1 rows 32..63
    const int scs0 = ((lane & 7) ^ (sr0 & 7)) * 8;  // swizzled col (shorts)
    const int scs1 = ((lane & 7) ^ (sr1 & 7)) * 8;
    const short* Kg = Kb + kvbase;
    const short* Vg = Vtb + kvbase;

    // read-side swizzle constants
    const int rs_ = ac & 7;
    const int ca_ = al ^ rs_;
    const int ch_ = al >> 1;
    const int inner_ = (al & 1) * 4;

    const short* qp = Qb + kvbase + (q0 + ac) * 64 + al * 8;
    const bf16x8 qf0 = *(const bf16x8*)qp;
    const bf16x8 qf1 = *(const bf16x8*)(qp + 32);
    __builtin_amdgcn_sched_barrier(0);
    STAGE(0, 0);
    __builtin_amdgcn_sched_barrier(0);
    const float* bp = bias + ((long long)bh * 2048 + q0 + ac) * 2048 + al * 4;
    f32x4 bcA[4], bcB[4];
#pragma unroll
    for (int ni = 0; ni < 4; ni++)
        bcA[ni] = __builtin_nontemporal_load((const f32x4*)&bp[ni * 16]);
    // drain qf+stage (oldest 6), keep the 4 bias loads in flight
    asm volatile("s_waitcnt vmcnt(4)" ::: "memory");
    __builtin_amdgcn_s_barrier();
    __builtin_amdgcn_sched_barrier(0);

    float m_i = -1e30f, l_i = 0.f;
    f32x4 o[4];
#pragma unroll
    for (int i = 0; i < 4; i++) o[i] = (f32x4){0.f, 0.f, 0.f, 0.f};

#pragma unroll 1
    for (int t = 0; t < 32; t += 2) {
        ATTN_STEP(t, 0, bcA, bcB);
        ATTN_STEP(t + 1, 1, bcB, bcA);
    }

    float lt = l_i + __shfl_xor(l_i, 16);
    lt += __shfl_xor(lt, 32);
    const float inv = 1.f / lt;
    const int b_ = bh >> 4, h_ = bh & 15;
    short* cp = Ctx + (long long)(b_ * 2048 + q0) * 1024 + h_ * 64 + ac;
#pragma unroll
    for (int r = 0; r < 4; r++) {
        const float ir_ = __shfl(inv, al20 + r);
        const int row = al * 4 + r;
#pragma unroll
        for (int nd = 0; nd < 4; nd++)
            cp[(long long)row * 1024 + nd * 16] = f2bf(o[nd][r] * ir_);
    }
}

// ---------------- GEMM2: out = Ctx @ Wo^T + bo (fp32 out) ----------------
__global__ __launch_bounds__(256, 2) void gemm_out_kernel(
    const short* __restrict__ A, const short* __restrict__ W,
    const float* __restrict__ bias, float* __restrict__ out) {
    __shared__ short As[128 * 32];
    __shared__ short Bs[128 * 32];
    __shared__ float scrF[4][16 * 28];  // per-wave fp32 repack, stride 28
    const int tid = threadIdx.x;
    const int wave = tid >> 6, lane = tid & 63;
    const int al = lane >> 4, ac = lane & 15;
    const int m0 = blockIdx.x * 128;
    const int n0 = blockIdx.y * 128;
    const int wm = wave & 1, wn = wave >> 1;

    const int crow = tid >> 2, ccol = (tid & 3) * 8;
    const short* Ag0 = A + (m0 + crow) * 1024 + ccol;
    const short* Ag1 = A + (m0 + crow + 64) * 1024 + ccol;
    const short* Wg0 = W + (n0 + crow) * 1024 + ccol;
    const short* Wg1 = W + (n0 + crow + 64) * 1024 + ccol;
    short* lA0 = &As[wave * 512];
    short* lA1 = &As[2048 + wave * 512];
    short* lB0 = &Bs[wave * 512];
    short* lB1 = &Bs[2048 + wave * 512];

    f32x4 acc[4][4];
#pragma unroll
    for (int mi = 0; mi < 4; mi++)
#pragma unroll
        for (int ni = 0; ni < 4; ni++) acc[mi][ni] = (f32x4){0.f, 0.f, 0.f, 0.f};

    for (int k0 = 0; k0 < 1024; k0 += 32) {
        __syncthreads();
        g2l16(Ag0 + k0, lA0);
        g2l16(Ag1 + k0, lA1);
        g2l16(Wg0 + k0, lB0);
        g2l16(Wg1 + k0, lB1);
        __syncthreads();
        bf16x8 af[4], bfr[4];
#pragma unroll
        for (int i = 0; i < 4; i++) {
            af[i] = *(const bf16x8*)&As[(wm * 64 + i * 16 + ac) * 32 + al * 8];
            bfr[i] = *(const bf16x8*)&Bs[(wn * 64 + i * 16 + ac) * 32 + al * 8];
        }
#pragma unroll
        for (int mi = 0; mi < 4; mi++)
#pragma unroll
            for (int ni = 0; ni < 4; ni++)
                acc[mi][ni] = MFMA(af[mi], bfr[ni], acc[mi][ni]);
    }

    float* scr = scrF[wave];
    const int lr = lane >> 2, lq = lane & 3;
#pragma unroll
    for (int mi = 0; mi < 4; mi++) {
#pragma unroll
        for (int ni = 0; ni < 4; ni++) {
            const int col0 = n0 + wn * 64 + ni * 16;
            const float bvc = bias[col0 + ac];
#pragma unroll
            for (int r = 0; r < 4; r++)
                scr[(al * 4 + r) * 28 + ac] = acc[mi][ni][r] + bvc;
            f32x4 v4 = *(const f32x4*)&scr[lr * 28 + lq * 4];
            const int row = m0 + wm * 64 + mi * 16 + lr;
            *(f32x4*)&out[row * 1024 + col0 + lq * 4] = v4;
        }
    }
}

extern "C" void kernel_launch(void* const* d_in, const int* in_sizes, int n_in,
                              void* d_out, int out_size, void* d_ws,
                              size_t ws_size, hipStream_t stream) {
    const float* X = (const float*)d_in[0];
    const float* keb = (const float*)d_in[1];
    const float* Wi = (const float*)d_in[2];
    const float* bi = (const float*)d_in[3];
    const float* Wo = (const float*)d_in[4];
    const float* bo = (const float*)d_in[5];
    float* out = (float*)d_out;

    char* ws = (char*)d_ws;
    short* Xb  = (short*)(ws);              //  8 MB  [4096,1024]
    short* Wib = (short*)(ws + 8388608);    //  6 MB  [3072,1024]
    short* Wob = (short*)(ws + 14680064);   //  2 MB  [1024,1024]
    short* Qb  = (short*)(ws + 16777216);   //  8 MB  [bh][l][d] (pre-scaled by 0.125*log2e)
    short* Kb  = (short*)(ws + 25165824);   //  8 MB  [bh][l][d]
    short* Vtb = (short*)(ws + 33554432);   //  8 MB  [bh][d][l]
    short* Ctx = (short*)(ws + 41943040);   //  8 MB  [4096,1024]

    cvt_bf16_kernel<<<dim3(524288 / 256), 256, 0, stream>>>(X, Xb, 524288);
    cvt_bf16_kernel<<<dim3(393216 / 256), 256, 0, stream>>>(Wi, Wib, 393216);
    cvt_bf16_kernel<<<dim3(131072 / 256), 256, 0, stream>>>(Wo, Wob, 131072);
    gemm_qkv_kernel<<<dim3(32, 24), 256, 0, stream>>>(Xb, Wib, bi, Qb, Kb, Vtb);
    attn_kernel<<<dim3(1024), 256, 0, stream>>>(Qb, Kb, Vtb, keb, Ctx);
    gemm_out_kernel<<<dim3(32, 8), 256, 0, stream>>>(Ctx, Wob, bo, out);
}